// Round 7
// baseline (1162.606 us; speedup 1.0000x reference)
//
#include <hip/hip_runtime.h>
#include <math.h>

#define N_NODES 100000
#define N_EDGES 3200000
#define NEG 0.2f

typedef __attribute__((ext_vector_type(8))) short short8;
typedef __attribute__((ext_vector_type(4))) float f32x4;
typedef __attribute__((ext_vector_type(4))) unsigned int u32x4;

__device__ __forceinline__ float lrelu(float x){ return x > 0.f ? x : NEG * x; }
__device__ __forceinline__ float bflo(unsigned int u){
  union { unsigned int i; float f; } v; v.i = u << 16; return v.f;
}
__device__ __forceinline__ float bfhi(unsigned int u){
  union { unsigned int i; float f; } v; v.i = u & 0xffff0000u; return v.f;
}
__device__ __forceinline__ float bfus(unsigned short u){
  union { unsigned int i; float f; } v; v.i = ((unsigned int)u) << 16; return v.f;
}
__device__ __forceinline__ unsigned short f2bf(float f){
  union { float f; unsigned int i; } v; v.f = f;
  unsigned int r = v.i + 0x7fffu + ((v.i >> 16) & 1u);
  return (unsigned short)(r >> 16);
}
__device__ __forceinline__ unsigned int packbf(float lo, float hi){
  return (unsigned int)f2bf(lo) | ((unsigned int)f2bf(hi) << 16);
}

// ---- weight prep ----
__global__ void k_cvtW1(const float* __restrict__ W, unsigned short* __restrict__ Wt){
  int i = blockIdx.x*256 + threadIdx.x;
  if (i < 512*128){ int n = i >> 7, k = i & 127; Wt[i] = f2bf(W[k*512 + n]); }
}
__global__ void k_cvtW2(const float* __restrict__ W, unsigned short* __restrict__ Wt){
  int i = blockIdx.x*256 + threadIdx.x;
  if (i < 64*512){ int n = i >> 9, k = i & 511; Wt[i] = f2bf(W[k*64 + n]); }
}

// ---- GEMM1 (MFMA) + fused layer-1 scores ----
// x fp32 [M][128] @ W1t bf16 -> feat1 bf16 [M][512] node-major; el/er (N,4).
// block 256 (4 waves), tile 128(M) x 128(N); N-tile == one head (blockIdx.y).
__global__ __launch_bounds__(256) void k_mm1(const float* __restrict__ A,
    const unsigned short* __restrict__ Bt,
    unsigned short* __restrict__ C, int M,
    const float* __restrict__ al, const float* __restrict__ ar,
    float* __restrict__ el, float* __restrict__ er){
  __shared__ unsigned short sm[18432];          // As 128x72 | Bs 128x72 (36.9 KB)
  unsigned short* As = sm;
  unsigned short* Bs = sm + 9216;
  const int t = threadIdx.x;
  const int w = t >> 6, l = t & 63;
  const int quad = l >> 4, l16 = l & 15;
  const int m0 = blockIdx.x * 128;
  const int head = blockIdx.y;
  const int moff = (w & 1) * 64, noff = (w >> 1) * 64;
  f32x4 acc[4][4];
  #pragma unroll
  for (int i=0;i<4;++i)
    #pragma unroll
    for (int j=0;j<4;++j){ acc[i][j][0]=0.f; acc[i][j][1]=0.f; acc[i][j][2]=0.f; acc[i][j][3]=0.f; }
  for (int kb = 0; kb < 2; ++kb){
    const int K0 = kb * 64;
    #pragma unroll
    for (int i=0;i<8;++i){              // A: 128x64 fp32 -> bf16 LDS
      int idx = t + i*256;
      int row = idx >> 4, c4 = (idx & 15) * 4;
      float4 v = make_float4(0.f,0.f,0.f,0.f);
      if (m0 + row < M) v = *(const float4*)(A + (size_t)(m0+row)*128 + K0 + c4);
      uint2 p; p.x = packbf(v.x, v.y); p.y = packbf(v.z, v.w);
      *(uint2*)(As + row*72 + c4) = p;
    }
    #pragma unroll
    for (int i=0;i<4;++i){              // B: 128x64 bf16 copy
      int idx = t + i*256;
      int row = idx >> 3, c8 = (idx & 7) * 8;
      *(uint4*)(Bs + row*72 + c8) =
        *(const uint4*)(Bt + (size_t)(head*128 + row)*128 + K0 + c8);
    }
    __syncthreads();
    #pragma unroll
    for (int ks = 0; ks < 2; ++ks){
      short8 af[4], bfr[4];
      #pragma unroll
      for (int mi=0; mi<4; ++mi)
        af[mi] = *(const short8*)(As + (moff + mi*16 + l16)*72 + ks*32 + quad*8);
      #pragma unroll
      for (int ni=0; ni<4; ++ni)
        bfr[ni] = *(const short8*)(Bs + (noff + ni*16 + l16)*72 + ks*32 + quad*8);
      #pragma unroll
      for (int mi=0; mi<4; ++mi)
        #pragma unroll
        for (int ni=0; ni<4; ++ni)
          acc[mi][ni] = __builtin_amdgcn_mfma_f32_16x16x32_bf16(af[mi], bfr[ni], acc[mi][ni], 0,0,0);
    }
    __syncthreads();
  }
  // epilogue: bf16 repack via LDS
  unsigned short* Cs = sm;                       // 128x136 bf16 (34.8 KB)
  #pragma unroll
  for (int mi=0; mi<4; ++mi)
    #pragma unroll
    for (int ni=0; ni<4; ++ni){
      int col = noff + ni*16 + l16;
      int rb  = moff + mi*16 + quad*4;
      #pragma unroll
      for (int r=0;r<4;++r) Cs[(rb+r)*136 + col] = f2bf(acc[mi][ni][r]);
    }
  __syncthreads();
  const int hcol = head * 128;
  #pragma unroll
  for (int i=0;i<8;++i){                // 128x128 / 8 per-thread / 256 thr = 8
    int e = t + i*256;
    int row = e >> 4, c8 = (e & 15) * 8;
    if (m0 + row < M)
      *(uint4*)(C + (size_t)(m0+row)*512 + hcol + c8) = *(const uint4*)(Cs + row*136 + c8);
  }
  // fused scores: thread pair (t, t^1) covers one row (64 cols each)
  {
    int row = t >> 1, half = t & 1;
    const float* alp = al + head*128 + half*64;
    const float* arp = ar + head*128 + half*64;
    const unsigned short* cp = Cs + row*136 + half*64;
    float se = 0.f, sr = 0.f;
    #pragma unroll
    for (int i=0;i<8;++i){
      uint4 q = *(const uint4*)(cp + i*8);
      float4 a0 = *(const float4*)(alp + i*8), a1 = *(const float4*)(alp + i*8 + 4);
      float4 r0 = *(const float4*)(arp + i*8), r1 = *(const float4*)(arp + i*8 + 4);
      se += bflo(q.x)*a0.x + bfhi(q.x)*a0.y + bflo(q.y)*a0.z + bfhi(q.y)*a0.w
          + bflo(q.z)*a1.x + bfhi(q.z)*a1.y + bflo(q.w)*a1.z + bfhi(q.w)*a1.w;
      sr += bflo(q.x)*r0.x + bfhi(q.x)*r0.y + bflo(q.y)*r0.z + bfhi(q.y)*r0.w
          + bflo(q.z)*r1.x + bfhi(q.z)*r1.y + bflo(q.w)*r1.z + bfhi(q.w)*r1.w;
    }
    se += __shfl_xor(se, 1); sr += __shfl_xor(sr, 1);
    if (half == 0 && m0 + row < M){
      el[(m0+row)*4 + head] = se;
      er[(m0+row)*4 + head] = sr;
    }
  }
}

// ---- GEMM2 (MFMA) + fused layer-2 scores ----
// h1 bf16 [M][512] @ W2t bf16 -> feat2b bf16 [M][64]; el2/er2 (N,).
__global__ __launch_bounds__(256) void k_mm2(const unsigned short* __restrict__ A,
    const unsigned short* __restrict__ Bt,
    unsigned short* __restrict__ C, int M,
    const float* __restrict__ al, const float* __restrict__ ar,
    float* __restrict__ el, float* __restrict__ er){
  __shared__ unsigned short sm[13824];          // As 128x72 | Bs 64x72 (27.6 KB)
  unsigned short* As = sm;
  unsigned short* Bs = sm + 9216;
  const int t = threadIdx.x;
  const int w = t >> 6, l = t & 63;
  const int quad = l >> 4, l16 = l & 15;
  const int m0 = blockIdx.x * 128;
  const int moff = w * 32;
  f32x4 acc[2][4];
  #pragma unroll
  for (int i=0;i<2;++i)
    #pragma unroll
    for (int j=0;j<4;++j){ acc[i][j][0]=0.f; acc[i][j][1]=0.f; acc[i][j][2]=0.f; acc[i][j][3]=0.f; }
  for (int kb = 0; kb < 8; ++kb){
    const int K0 = kb * 64;
    #pragma unroll
    for (int i=0;i<4;++i){
      int idx = t + i*256;
      int row = idx >> 3, c8 = (idx & 7) * 8;
      uint4 v; v.x=0u; v.y=0u; v.z=0u; v.w=0u;
      if (m0 + row < M) v = *(const uint4*)(A + (size_t)(m0+row)*512 + K0 + c8);
      *(uint4*)(As + row*72 + c8) = v;
    }
    #pragma unroll
    for (int i=0;i<2;++i){
      int idx = t + i*256;
      int row = idx >> 3, c8 = (idx & 7) * 8;
      *(uint4*)(Bs + row*72 + c8) = *(const uint4*)(Bt + (size_t)row*512 + K0 + c8);
    }
    __syncthreads();
    #pragma unroll
    for (int ks = 0; ks < 2; ++ks){
      short8 af[2], bfr[4];
      #pragma unroll
      for (int mi=0; mi<2; ++mi)
        af[mi] = *(const short8*)(As + (moff + mi*16 + l16)*72 + ks*32 + quad*8);
      #pragma unroll
      for (int ni=0; ni<4; ++ni)
        bfr[ni] = *(const short8*)(Bs + (ni*16 + l16)*72 + ks*32 + quad*8);
      #pragma unroll
      for (int mi=0; mi<2; ++mi)
        #pragma unroll
        for (int ni=0; ni<4; ++ni)
          acc[mi][ni] = __builtin_amdgcn_mfma_f32_16x16x32_bf16(af[mi], bfr[ni], acc[mi][ni], 0,0,0);
    }
    __syncthreads();
  }
  unsigned short* Cs = sm;                       // 128x72 bf16
  #pragma unroll
  for (int mi=0; mi<2; ++mi)
    #pragma unroll
    for (int ni=0; ni<4; ++ni){
      int col = ni*16 + l16;
      int rb  = moff + mi*16 + quad*4;
      #pragma unroll
      for (int r=0;r<4;++r) Cs[(rb+r)*72 + col] = f2bf(acc[mi][ni][r]);
    }
  __syncthreads();
  #pragma unroll
  for (int i=0;i<4;++i){
    int e = t + i*256;
    int row = e >> 3, c8 = (e & 7) * 8;
    if (m0 + row < M)
      *(uint4*)(C + (size_t)(m0+row)*64 + c8) = *(const uint4*)(Cs + row*72 + c8);
  }
  // fused scores: thread pair covers one row (32 cols each)
  {
    int row = t >> 1, half = t & 1;
    const float* alp = al + half*32;
    const float* arp = ar + half*32;
    const unsigned short* cp = Cs + row*72 + half*32;
    float se = 0.f, sr = 0.f;
    #pragma unroll
    for (int i=0;i<4;++i){
      uint4 q = *(const uint4*)(cp + i*8);
      float4 a0 = *(const float4*)(alp + i*8), a1 = *(const float4*)(alp + i*8 + 4);
      float4 r0 = *(const float4*)(arp + i*8), r1 = *(const float4*)(arp + i*8 + 4);
      se += bflo(q.x)*a0.x + bfhi(q.x)*a0.y + bflo(q.y)*a0.z + bfhi(q.y)*a0.w
          + bflo(q.z)*a1.x + bfhi(q.z)*a1.y + bflo(q.w)*a1.z + bfhi(q.w)*a1.w;
      sr += bflo(q.x)*r0.x + bfhi(q.x)*r0.y + bflo(q.y)*r0.z + bfhi(q.y)*r0.w
          + bflo(q.z)*r1.x + bfhi(q.z)*r1.y + bflo(q.w)*r1.z + bfhi(q.w)*r1.w;
    }
    se += __shfl_xor(se, 1); sr += __shfl_xor(sr, 1);
    if (half == 0 && m0 + row < M){
      el[m0+row] = se;
      er[m0+row] = sr;
    }
  }
}

// ---- CSR build ----
__global__ void k_zero(int* __restrict__ p, int n){
  int i = blockIdx.x*blockDim.x + threadIdx.x;
  if (i < n) p[i] = 0;
}
__global__ void k_count(const int* __restrict__ dst, int* __restrict__ deg){
  int e = blockIdx.x*blockDim.x + threadIdx.x;
  if (e < N_EDGES) atomicAdd(&deg[dst[e]], 1);
}
__global__ __launch_bounds__(1024) void k_scan1(const int* __restrict__ deg,
    int* __restrict__ indptr, int* __restrict__ bsum){
  __shared__ int lds[1024];
  int t = threadIdx.x, i = blockIdx.x*1024 + t;
  int v = (i < N_NODES) ? deg[i] : 0;
  lds[t] = v; __syncthreads();
  for (int off=1; off<1024; off<<=1){
    int u = (t>=off)? lds[t-off] : 0;
    __syncthreads();
    lds[t] += u;
    __syncthreads();
  }
  if (i < N_NODES) indptr[i] = lds[t] - v;
  if (t == 1023) bsum[blockIdx.x] = lds[1023];
}
__global__ void k_scan2(const int* __restrict__ bsum, int* __restrict__ boff, int nb){
  __shared__ int lds[128];
  int t = threadIdx.x;
  int v = (t < nb) ? bsum[t] : 0;
  lds[t] = v; __syncthreads();
  for (int off=1; off<128; off<<=1){
    int u = (t>=off)? lds[t-off] : 0;
    __syncthreads();
    lds[t] += u;
    __syncthreads();
  }
  if (t < nb) boff[t] = lds[t] - v;
}
__global__ void k_scan3(int* __restrict__ indptr, const int* __restrict__ boff,
                        int* __restrict__ cursor){
  int i = blockIdx.x*blockDim.x + threadIdx.x;
  if (i < N_NODES){
    int v = indptr[i] + boff[i>>10];
    indptr[i] = v;
    cursor[i] = v;
  }
  if (i == N_NODES) indptr[N_NODES] = N_EDGES;
}
__global__ void k_scatter(const int* __restrict__ src, const int* __restrict__ dst,
                          int* __restrict__ cursor, int* __restrict__ csr_src){
  int e = blockIdx.x*blockDim.x + threadIdx.x;
  if (e < N_EDGES){
    int d = dst[e];
    int pos = atomicAdd(&cursor[d], 1);
    csr_src[pos] = src[e];
  }
}

// ---- layer-1 aggregate + ELU: one-pass online softmax, wave per node ----
// feat node-major [N][512] bf16 (keep cached); h1 out via NON-TEMPORAL store
// (don't evict feat1 from L3); csr_src via nt loads (streamed once).
__global__ __launch_bounds__(256) void k_agg1(const unsigned short* __restrict__ feat,
    const float* __restrict__ el, const float* __restrict__ er,
    const int* __restrict__ indptr, const int* __restrict__ csr_src,
    unsigned short* __restrict__ out){
  int wave = threadIdx.x >> 6, lane = threadIdx.x & 63;
  int n = blockIdx.x*4 + wave;
  if (n >= N_NODES) return;
  int p0 = indptr[n], p1 = indptr[n+1];
  const int hh = lane >> 4;
  const int d0 = lane * 8;
  const float myer = er[n*4 + hh];
  float ssum = 0.f;
  float acc[8] = {0.f,0.f,0.f,0.f,0.f,0.f,0.f,0.f};
  int e = p0;
  for (; e + 1 < p1; e += 2){
    int s0 = __builtin_nontemporal_load(csr_src + e);
    int s1 = __builtin_nontemporal_load(csr_src + e + 1);
    float w0 = __expf(lrelu(el[s0*4 + hh] + myer));
    float w1 = __expf(lrelu(el[s1*4 + hh] + myer));
    uint4 q0 = *(const uint4*)(feat + (size_t)s0*512 + d0);
    uint4 q1 = *(const uint4*)(feat + (size_t)s1*512 + d0);
    ssum += w0 + w1;
    acc[0] += w0*bflo(q0.x) + w1*bflo(q1.x);
    acc[1] += w0*bfhi(q0.x) + w1*bfhi(q1.x);
    acc[2] += w0*bflo(q0.y) + w1*bflo(q1.y);
    acc[3] += w0*bfhi(q0.y) + w1*bfhi(q1.y);
    acc[4] += w0*bflo(q0.z) + w1*bflo(q1.z);
    acc[5] += w0*bfhi(q0.z) + w1*bfhi(q1.z);
    acc[6] += w0*bflo(q0.w) + w1*bflo(q1.w);
    acc[7] += w0*bfhi(q0.w) + w1*bfhi(q1.w);
  }
  if (e < p1){
    int s0 = __builtin_nontemporal_load(csr_src + e);
    float w0 = __expf(lrelu(el[s0*4 + hh] + myer));
    uint4 q0 = *(const uint4*)(feat + (size_t)s0*512 + d0);
    ssum += w0;
    acc[0] += w0*bflo(q0.x); acc[1] += w0*bfhi(q0.x);
    acc[2] += w0*bflo(q0.y); acc[3] += w0*bfhi(q0.y);
    acc[4] += w0*bflo(q0.z); acc[5] += w0*bfhi(q0.z);
    acc[6] += w0*bflo(q0.w); acc[7] += w0*bfhi(q0.w);
  }
  float inv = ssum > 0.f ? 1.f/ssum : 0.f;
  #pragma unroll
  for (int i=0;i<8;++i){
    float v = acc[i] * inv;
    acc[i] = v > 0.f ? v : __expf(v) - 1.f;   // fused ELU
  }
  u32x4 o;
  o.x = packbf(acc[0],acc[1]); o.y = packbf(acc[2],acc[3]);
  o.z = packbf(acc[4],acc[5]); o.w = packbf(acc[6],acc[7]);
  __builtin_nontemporal_store(o, (u32x4*)(out + (size_t)n*512 + d0));
}

// ---- layer-2 aggregate: one-pass, wave per node, eighth-wave per edge ----
__global__ __launch_bounds__(256) void k_agg2(const unsigned short* __restrict__ feat,
    const float* __restrict__ el, const float* __restrict__ er,
    const int* __restrict__ indptr, const int* __restrict__ csr_src,
    float* __restrict__ out){
  int wave = threadIdx.x >> 6, lane = threadIdx.x & 63;
  int n = blockIdx.x*4 + wave;
  if (n >= N_NODES) return;
  int p0 = indptr[n], p1 = indptr[n+1];
  float ern = er[n];
  int g = lane >> 3, ql = lane & 7;
  float s = 0.f;
  float acc[8] = {0.f,0.f,0.f,0.f,0.f,0.f,0.f,0.f};
  for (int e = p0 + g; e < p1; e += 8){
    int si = __builtin_nontemporal_load(csr_src + e);
    float w = __expf(lrelu(el[si] + ern));
    uint4 v = *(const uint4*)(feat + (size_t)si*64 + ql*8);
    s += w;
    acc[0] += w*bflo(v.x); acc[1] += w*bfhi(v.x);
    acc[2] += w*bflo(v.y); acc[3] += w*bfhi(v.y);
    acc[4] += w*bflo(v.z); acc[5] += w*bfhi(v.z);
    acc[6] += w*bflo(v.w); acc[7] += w*bfhi(v.w);
  }
  #pragma unroll
  for (int m=8;m<64;m<<=1){
    s += __shfl_xor(s,m);
    #pragma unroll
    for (int i=0;i<8;++i) acc[i] += __shfl_xor(acc[i],m);
  }
  float inv = s > 0.f ? 1.f/s : 0.f;
  if (g == 0){
    float* op = out + (size_t)n*64 + ql*8;
    f32x4 o0, o1;
    o0[0]=acc[0]*inv; o0[1]=acc[1]*inv; o0[2]=acc[2]*inv; o0[3]=acc[3]*inv;
    o1[0]=acc[4]*inv; o1[1]=acc[5]*inv; o1[2]=acc[6]*inv; o1[3]=acc[7]*inv;
    __builtin_nontemporal_store(o0, (f32x4*)op);
    __builtin_nontemporal_store(o1, (f32x4*)(op+4));
  }
}

extern "C" void kernel_launch(void* const* d_in, const int* in_sizes, int n_in,
                              void* d_out, int out_size, void* d_ws, size_t ws_size,
                              hipStream_t stream){
  const float* x   = (const float*)d_in[0];
  const float* W1  = (const float*)d_in[1];
  const float* al1 = (const float*)d_in[2];
  const float* ar1 = (const float*)d_in[3];
  const float* W2  = (const float*)d_in[4];
  const float* al2 = (const float*)d_in[5];
  const float* ar2 = (const float*)d_in[6];
  const int* src   = (const int*)d_in[7];
  const int* dst   = (const int*)d_in[8];
  float* out = (float*)d_out;

  char* ws = (char*)d_ws;
  size_t off = 0;
  auto alloc = [&](size_t bytes)->char*{
    char* p = ws + off; off += (bytes + 255) & ~(size_t)255; return p;
  };
  unsigned short* feat1 = (unsigned short*)alloc((size_t)N_NODES*512*2);  // 102.4 MB
  unsigned short* h1    = (unsigned short*)alloc((size_t)N_NODES*512*2);  // 102.4 MB
  unsigned short* feat2b = feat1;             // alias: feat1 dead after k_agg1
  unsigned short* W1t = (unsigned short*)alloc(512*128*2);
  unsigned short* W2t = (unsigned short*)alloc(64*512*2);
  float* el1 = (float*)alloc((size_t)N_NODES*4*4);
  float* er1 = (float*)alloc((size_t)N_NODES*4*4);
  float* el2 = el1;                           // alias: el1 dead after k_agg1
  float* er2 = er1;
  int* deg     = (int*)alloc((size_t)N_NODES*4);
  int* indptr  = (int*)alloc((size_t)(N_NODES+1)*4);
  int* cursor  = (int*)alloc((size_t)N_NODES*4);
  int* bsum    = (int*)alloc(512);
  int* boff    = (int*)alloc(512);
  int* csr_src = (int*)alloc((size_t)N_EDGES*4);                          // 12.8 MB
  // total ~222 MB (footprint proven in rounds 3/5/6)

  dim3 b256(256);
  k_zero<<<dim3((N_NODES+255)/256), b256, 0, stream>>>(deg, N_NODES);
  k_cvtW1<<<dim3(256), b256, 0, stream>>>(W1, W1t);
  k_cvtW2<<<dim3(128), b256, 0, stream>>>(W2, W2t);
  // layer 1 projection (MFMA) + fused scores
  k_mm1<<<dim3(782, 4), b256, 0, stream>>>(x, W1t, feat1, N_NODES, al1, ar1, el1, er1);
  // dst-CSR
  k_count<<<dim3((N_EDGES+255)/256), b256, 0, stream>>>(dst, deg);
  k_scan1<<<dim3(98), dim3(1024), 0, stream>>>(deg, indptr, bsum);
  k_scan2<<<dim3(1), dim3(128), 0, stream>>>(bsum, boff, 98);
  k_scan3<<<dim3((N_NODES+256)/256), b256, 0, stream>>>(indptr, boff, cursor);
  k_scatter<<<dim3((N_EDGES+255)/256), b256, 0, stream>>>(src, dst, cursor, csr_src);
  // layer-1 aggregate + ELU (single-pass, nt h1 stores)
  k_agg1<<<dim3(25000), b256, 0, stream>>>(feat1, el1, er1, indptr, csr_src, h1);
  // layer 2 (MFMA) + fused scores
  k_mm2<<<dim3(782), b256, 0, stream>>>(h1, W2t, feat2b, N_NODES, al2, ar2, el2, er2);
  k_agg2<<<dim3(25000), b256, 0, stream>>>(feat2b, el2, er2, indptr, csr_src, out);
}

// Round 8
// 955.581 us; speedup vs baseline: 1.2166x; 1.2166x over previous
//
#include <hip/hip_runtime.h>
#include <math.h>

#define N_NODES 100000
#define N_EDGES 3200000
#define NEG 0.2f

typedef __attribute__((ext_vector_type(8))) short short8;
typedef __attribute__((ext_vector_type(4))) float f32x4;
typedef __attribute__((ext_vector_type(2))) float f32x2;

__device__ __forceinline__ float lrelu(float x){ return x > 0.f ? x : NEG * x; }
__device__ __forceinline__ float bflo(unsigned int u){
  union { unsigned int i; float f; } v; v.i = u << 16; return v.f;
}
__device__ __forceinline__ float bfhi(unsigned int u){
  union { unsigned int i; float f; } v; v.i = u & 0xffff0000u; return v.f;
}
__device__ __forceinline__ unsigned short f2bf(float f){
  union { float f; unsigned int i; } v; v.f = f;
  unsigned int r = v.i + 0x7fffu + ((v.i >> 16) & 1u);
  return (unsigned short)(r >> 16);
}
__device__ __forceinline__ unsigned int packbf(float lo, float hi){
  return (unsigned int)f2bf(lo) | ((unsigned int)f2bf(hi) << 16);
}
// 4x fp32 -> packed OCP e4m3 dword (HW cvt, gfx950)
__device__ __forceinline__ unsigned int pk_fp8x4(float a, float b, float c, float d){
  int v = 0;
  v = __builtin_amdgcn_cvt_pk_fp8_f32(a, b, v, false);
  v = __builtin_amdgcn_cvt_pk_fp8_f32(c, d, v, true);
  return (unsigned int)v;
}
__device__ __forceinline__ f32x2 unpk_fp8_lo(unsigned int v){
  return __builtin_amdgcn_cvt_pk_f32_fp8((int)v, false);
}
__device__ __forceinline__ f32x2 unpk_fp8_hi(unsigned int v){
  return __builtin_amdgcn_cvt_pk_f32_fp8((int)v, true);
}

// ---- weight prep ----
__global__ void k_cvtW1(const float* __restrict__ W, unsigned short* __restrict__ Wt){
  int i = blockIdx.x*256 + threadIdx.x;
  if (i < 512*128){ int n = i >> 7, k = i & 127; Wt[i] = f2bf(W[k*512 + n]); }
}
__global__ void k_cvtW2(const float* __restrict__ W, unsigned short* __restrict__ Wt){
  int i = blockIdx.x*256 + threadIdx.x;
  if (i < 64*512){ int n = i >> 9, k = i & 511; Wt[i] = f2bf(W[k*64 + n]); }
}

// ---- GEMM1 (MFMA) + fused layer-1 scores; feat1 stored as fp8 e4m3 ----
// x fp32 [M][128] @ W1t bf16 -> feat1 fp8 [M][512] node-major; el/er (N,4) fp32
// computed from pre-quantization values. tile 128x128; N-tile == head.
__global__ __launch_bounds__(256) void k_mm1(const float* __restrict__ A,
    const unsigned short* __restrict__ Bt,
    unsigned char* __restrict__ C8, int M,
    const float* __restrict__ al, const float* __restrict__ ar,
    float* __restrict__ el, float* __restrict__ er){
  __shared__ unsigned short sm[18432];          // As 128x72 | Bs 128x72 (36.9 KB)
  unsigned short* As = sm;
  unsigned short* Bs = sm + 9216;
  const int t = threadIdx.x;
  const int w = t >> 6, l = t & 63;
  const int quad = l >> 4, l16 = l & 15;
  const int m0 = blockIdx.x * 128;
  const int head = blockIdx.y;
  const int moff = (w & 1) * 64, noff = (w >> 1) * 64;
  f32x4 acc[4][4];
  #pragma unroll
  for (int i=0;i<4;++i)
    #pragma unroll
    for (int j=0;j<4;++j){ acc[i][j][0]=0.f; acc[i][j][1]=0.f; acc[i][j][2]=0.f; acc[i][j][3]=0.f; }
  for (int kb = 0; kb < 2; ++kb){
    const int K0 = kb * 64;
    #pragma unroll
    for (int i=0;i<8;++i){              // A: 128x64 fp32 -> bf16 LDS
      int idx = t + i*256;
      int row = idx >> 4, c4 = (idx & 15) * 4;
      float4 v = make_float4(0.f,0.f,0.f,0.f);
      if (m0 + row < M) v = *(const float4*)(A + (size_t)(m0+row)*128 + K0 + c4);
      uint2 p; p.x = packbf(v.x, v.y); p.y = packbf(v.z, v.w);
      *(uint2*)(As + row*72 + c4) = p;
    }
    #pragma unroll
    for (int i=0;i<4;++i){              // B: 128x64 bf16 copy
      int idx = t + i*256;
      int row = idx >> 3, c8 = (idx & 7) * 8;
      *(uint4*)(Bs + row*72 + c8) =
        *(const uint4*)(Bt + (size_t)(head*128 + row)*128 + K0 + c8);
    }
    __syncthreads();
    #pragma unroll
    for (int ks = 0; ks < 2; ++ks){
      short8 af[4], bfr[4];
      #pragma unroll
      for (int mi=0; mi<4; ++mi)
        af[mi] = *(const short8*)(As + (moff + mi*16 + l16)*72 + ks*32 + quad*8);
      #pragma unroll
      for (int ni=0; ni<4; ++ni)
        bfr[ni] = *(const short8*)(Bs + (noff + ni*16 + l16)*72 + ks*32 + quad*8);
      #pragma unroll
      for (int mi=0; mi<4; ++mi)
        #pragma unroll
        for (int ni=0; ni<4; ++ni)
          acc[mi][ni] = __builtin_amdgcn_mfma_f32_16x16x32_bf16(af[mi], bfr[ni], acc[mi][ni], 0,0,0);
    }
    __syncthreads();
  }
  // epilogue: bf16 repack via LDS (exact values for scores), fp8 global store
  unsigned short* Cs = sm;                       // 128x136 bf16 (34.8 KB)
  #pragma unroll
  for (int mi=0; mi<4; ++mi)
    #pragma unroll
    for (int ni=0; ni<4; ++ni){
      int col = noff + ni*16 + l16;
      int rb  = moff + mi*16 + quad*4;
      #pragma unroll
      for (int r=0;r<4;++r) Cs[(rb+r)*136 + col] = f2bf(acc[mi][ni][r]);
    }
  __syncthreads();
  const int hcol = head * 128;
  #pragma unroll
  for (int i=0;i<8;++i){                // 128 rows x 128 cols, 8 fp8/thread/iter
    int e = t + i*256;
    int row = e >> 4, c8 = (e & 15) * 8;
    uint4 qb = *(const uint4*)(Cs + row*136 + c8);
    uint2 o;
    o.x = pk_fp8x4(bflo(qb.x), bfhi(qb.x), bflo(qb.y), bfhi(qb.y));
    o.y = pk_fp8x4(bflo(qb.z), bfhi(qb.z), bflo(qb.w), bfhi(qb.w));
    if (m0 + row < M)
      *(uint2*)(C8 + (size_t)(m0+row)*512 + hcol + c8) = o;
  }
  // fused scores: thread pair (t, t^1) covers one row (64 cols each)
  {
    int row = t >> 1, half = t & 1;
    const float* alp = al + head*128 + half*64;
    const float* arp = ar + head*128 + half*64;
    const unsigned short* cp = Cs + row*136 + half*64;
    float se = 0.f, sr = 0.f;
    #pragma unroll
    for (int i=0;i<8;++i){
      uint4 q = *(const uint4*)(cp + i*8);
      float4 a0 = *(const float4*)(alp + i*8), a1 = *(const float4*)(alp + i*8 + 4);
      float4 r0 = *(const float4*)(arp + i*8), r1 = *(const float4*)(arp + i*8 + 4);
      se += bflo(q.x)*a0.x + bfhi(q.x)*a0.y + bflo(q.y)*a0.z + bfhi(q.y)*a0.w
          + bflo(q.z)*a1.x + bfhi(q.z)*a1.y + bflo(q.w)*a1.z + bfhi(q.w)*a1.w;
      sr += bflo(q.x)*r0.x + bfhi(q.x)*r0.y + bflo(q.y)*r0.z + bfhi(q.y)*r0.w
          + bflo(q.z)*r1.x + bfhi(q.z)*r1.y + bflo(q.w)*r1.z + bfhi(q.w)*r1.w;
    }
    se += __shfl_xor(se, 1); sr += __shfl_xor(sr, 1);
    if (half == 0 && m0 + row < M){
      el[(m0+row)*4 + head] = se;
      er[(m0+row)*4 + head] = sr;
    }
  }
}

// ---- GEMM2 (MFMA) + fused layer-2 scores ----
// h1 bf16 [M][512] @ W2t bf16 -> feat2b bf16 [M][64]; el2/er2 (N,).
__global__ __launch_bounds__(256) void k_mm2(const unsigned short* __restrict__ A,
    const unsigned short* __restrict__ Bt,
    unsigned short* __restrict__ C, int M,
    const float* __restrict__ al, const float* __restrict__ ar,
    float* __restrict__ el, float* __restrict__ er){
  __shared__ unsigned short sm[13824];          // As 128x72 | Bs 64x72 (27.6 KB)
  unsigned short* As = sm;
  unsigned short* Bs = sm + 9216;
  const int t = threadIdx.x;
  const int w = t >> 6, l = t & 63;
  const int quad = l >> 4, l16 = l & 15;
  const int m0 = blockIdx.x * 128;
  const int moff = w * 32;
  f32x4 acc[2][4];
  #pragma unroll
  for (int i=0;i<2;++i)
    #pragma unroll
    for (int j=0;j<4;++j){ acc[i][j][0]=0.f; acc[i][j][1]=0.f; acc[i][j][2]=0.f; acc[i][j][3]=0.f; }
  for (int kb = 0; kb < 8; ++kb){
    const int K0 = kb * 64;
    #pragma unroll
    for (int i=0;i<4;++i){
      int idx = t + i*256;
      int row = idx >> 3, c8 = (idx & 7) * 8;
      uint4 v; v.x=0u; v.y=0u; v.z=0u; v.w=0u;
      if (m0 + row < M) v = *(const uint4*)(A + (size_t)(m0+row)*512 + K0 + c8);
      *(uint4*)(As + row*72 + c8) = v;
    }
    #pragma unroll
    for (int i=0;i<2;++i){
      int idx = t + i*256;
      int row = idx >> 3, c8 = (idx & 7) * 8;
      *(uint4*)(Bs + row*72 + c8) = *(const uint4*)(Bt + (size_t)row*512 + K0 + c8);
    }
    __syncthreads();
    #pragma unroll
    for (int ks = 0; ks < 2; ++ks){
      short8 af[2], bfr[4];
      #pragma unroll
      for (int mi=0; mi<2; ++mi)
        af[mi] = *(const short8*)(As + (moff + mi*16 + l16)*72 + ks*32 + quad*8);
      #pragma unroll
      for (int ni=0; ni<4; ++ni)
        bfr[ni] = *(const short8*)(Bs + (ni*16 + l16)*72 + ks*32 + quad*8);
      #pragma unroll
      for (int mi=0; mi<2; ++mi)
        #pragma unroll
        for (int ni=0; ni<4; ++ni)
          acc[mi][ni] = __builtin_amdgcn_mfma_f32_16x16x32_bf16(af[mi], bfr[ni], acc[mi][ni], 0,0,0);
    }
    __syncthreads();
  }
  unsigned short* Cs = sm;                       // 128x72 bf16
  #pragma unroll
  for (int mi=0; mi<2; ++mi)
    #pragma unroll
    for (int ni=0; ni<4; ++ni){
      int col = ni*16 + l16;
      int rb  = moff + mi*16 + quad*4;
      #pragma unroll
      for (int r=0;r<4;++r) Cs[(rb+r)*72 + col] = f2bf(acc[mi][ni][r]);
    }
  __syncthreads();
  #pragma unroll
  for (int i=0;i<4;++i){
    int e = t + i*256;
    int row = e >> 3, c8 = (e & 7) * 8;
    if (m0 + row < M)
      *(uint4*)(C + (size_t)(m0+row)*64 + c8) = *(const uint4*)(Cs + row*72 + c8);
  }
  // fused scores: thread pair covers one row (32 cols each)
  {
    int row = t >> 1, half = t & 1;
    const float* alp = al + half*32;
    const float* arp = ar + half*32;
    const unsigned short* cp = Cs + row*72 + half*32;
    float se = 0.f, sr = 0.f;
    #pragma unroll
    for (int i=0;i<4;++i){
      uint4 q = *(const uint4*)(cp + i*8);
      float4 a0 = *(const float4*)(alp + i*8), a1 = *(const float4*)(alp + i*8 + 4);
      float4 r0 = *(const float4*)(arp + i*8), r1 = *(const float4*)(arp + i*8 + 4);
      se += bflo(q.x)*a0.x + bfhi(q.x)*a0.y + bflo(q.y)*a0.z + bfhi(q.y)*a0.w
          + bflo(q.z)*a1.x + bfhi(q.z)*a1.y + bflo(q.w)*a1.z + bfhi(q.w)*a1.w;
      sr += bflo(q.x)*r0.x + bfhi(q.x)*r0.y + bflo(q.y)*r0.z + bfhi(q.y)*r0.w
          + bflo(q.z)*r1.x + bfhi(q.z)*r1.y + bflo(q.w)*r1.z + bfhi(q.w)*r1.w;
    }
    se += __shfl_xor(se, 1); sr += __shfl_xor(sr, 1);
    if (half == 0 && m0 + row < M){
      el[m0+row] = se;
      er[m0+row] = sr;
    }
  }
}

// ---- CSR build ----
__global__ void k_zero(int* __restrict__ p, int n){
  int i = blockIdx.x*blockDim.x + threadIdx.x;
  if (i < n) p[i] = 0;
}
__global__ void k_count(const int* __restrict__ dst, int* __restrict__ deg){
  int e = blockIdx.x*blockDim.x + threadIdx.x;
  if (e < N_EDGES) atomicAdd(&deg[dst[e]], 1);
}
__global__ __launch_bounds__(1024) void k_scan1(const int* __restrict__ deg,
    int* __restrict__ indptr, int* __restrict__ bsum){
  __shared__ int lds[1024];
  int t = threadIdx.x, i = blockIdx.x*1024 + t;
  int v = (i < N_NODES) ? deg[i] : 0;
  lds[t] = v; __syncthreads();
  for (int off=1; off<1024; off<<=1){
    int u = (t>=off)? lds[t-off] : 0;
    __syncthreads();
    lds[t] += u;
    __syncthreads();
  }
  if (i < N_NODES) indptr[i] = lds[t] - v;
  if (t == 1023) bsum[blockIdx.x] = lds[1023];
}
__global__ void k_scan2(const int* __restrict__ bsum, int* __restrict__ boff, int nb){
  __shared__ int lds[128];
  int t = threadIdx.x;
  int v = (t < nb) ? bsum[t] : 0;
  lds[t] = v; __syncthreads();
  for (int off=1; off<128; off<<=1){
    int u = (t>=off)? lds[t-off] : 0;
    __syncthreads();
    lds[t] += u;
    __syncthreads();
  }
  if (t < nb) boff[t] = lds[t] - v;
}
__global__ void k_scan3(int* __restrict__ indptr, const int* __restrict__ boff,
                        int* __restrict__ cursor){
  int i = blockIdx.x*blockDim.x + threadIdx.x;
  if (i < N_NODES){
    int v = indptr[i] + boff[i>>10];
    indptr[i] = v;
    cursor[i] = v;
  }
  if (i == N_NODES) indptr[N_NODES] = N_EDGES;
}
__global__ void k_scatter(const int* __restrict__ src, const int* __restrict__ dst,
                          int* __restrict__ cursor, int* __restrict__ csr_src){
  int e = blockIdx.x*blockDim.x + threadIdx.x;
  if (e < N_EDGES){
    int d = dst[e];
    int pos = atomicAdd(&cursor[d], 1);
    csr_src[pos] = src[e];
  }
}

// ---- layer-1 aggregate + ELU: one-pass online softmax, wave per node ----
// feat fp8 [N][512]; lane covers 8 dims (uint2 = 8 fp8). 512 B/edge coalesced.
__global__ __launch_bounds__(256) void k_agg1(const unsigned char* __restrict__ feat,
    const float* __restrict__ el, const float* __restrict__ er,
    const int* __restrict__ indptr, const int* __restrict__ csr_src,
    unsigned short* __restrict__ out){
  int wave = threadIdx.x >> 6, lane = threadIdx.x & 63;
  int n = blockIdx.x*4 + wave;
  if (n >= N_NODES) return;
  int p0 = indptr[n], p1 = indptr[n+1];
  const int hh = lane >> 4;
  const int d0 = lane * 8;
  const float myer = er[n*4 + hh];
  float ssum = 0.f;
  float acc[8] = {0.f,0.f,0.f,0.f,0.f,0.f,0.f,0.f};
  int e = p0;
  for (; e + 1 < p1; e += 2){
    int s0 = csr_src[e], s1 = csr_src[e+1];
    float w0 = __expf(lrelu(el[s0*4 + hh] + myer));
    float w1 = __expf(lrelu(el[s1*4 + hh] + myer));
    uint2 q0 = *(const uint2*)(feat + (size_t)s0*512 + d0);
    uint2 q1 = *(const uint2*)(feat + (size_t)s1*512 + d0);
    ssum += w0 + w1;
    f32x2 a, b;
    a = unpk_fp8_lo(q0.x); b = unpk_fp8_lo(q1.x);
    acc[0] += w0*a[0] + w1*b[0]; acc[1] += w0*a[1] + w1*b[1];
    a = unpk_fp8_hi(q0.x); b = unpk_fp8_hi(q1.x);
    acc[2] += w0*a[0] + w1*b[0]; acc[3] += w0*a[1] + w1*b[1];
    a = unpk_fp8_lo(q0.y); b = unpk_fp8_lo(q1.y);
    acc[4] += w0*a[0] + w1*b[0]; acc[5] += w0*a[1] + w1*b[1];
    a = unpk_fp8_hi(q0.y); b = unpk_fp8_hi(q1.y);
    acc[6] += w0*a[0] + w1*b[0]; acc[7] += w0*a[1] + w1*b[1];
  }
  if (e < p1){
    int s0 = csr_src[e];
    float w0 = __expf(lrelu(el[s0*4 + hh] + myer));
    uint2 q0 = *(const uint2*)(feat + (size_t)s0*512 + d0);
    ssum += w0;
    f32x2 a;
    a = unpk_fp8_lo(q0.x); acc[0] += w0*a[0]; acc[1] += w0*a[1];
    a = unpk_fp8_hi(q0.x); acc[2] += w0*a[0]; acc[3] += w0*a[1];
    a = unpk_fp8_lo(q0.y); acc[4] += w0*a[0]; acc[5] += w0*a[1];
    a = unpk_fp8_hi(q0.y); acc[6] += w0*a[0]; acc[7] += w0*a[1];
  }
  float inv = ssum > 0.f ? 1.f/ssum : 0.f;
  #pragma unroll
  for (int i=0;i<8;++i){
    float v = acc[i] * inv;
    acc[i] = v > 0.f ? v : __expf(v) - 1.f;   // fused ELU
  }
  uint4 o;
  o.x = packbf(acc[0],acc[1]); o.y = packbf(acc[2],acc[3]);
  o.z = packbf(acc[4],acc[5]); o.w = packbf(acc[6],acc[7]);
  *(uint4*)(out + (size_t)n*512 + d0) = o;
}

// ---- layer-2 aggregate: one-pass, wave per node, eighth-wave per edge ----
__global__ __launch_bounds__(256) void k_agg2(const unsigned short* __restrict__ feat,
    const float* __restrict__ el, const float* __restrict__ er,
    const int* __restrict__ indptr, const int* __restrict__ csr_src,
    float* __restrict__ out){
  int wave = threadIdx.x >> 6, lane = threadIdx.x & 63;
  int n = blockIdx.x*4 + wave;
  if (n >= N_NODES) return;
  int p0 = indptr[n], p1 = indptr[n+1];
  float ern = er[n];
  int g = lane >> 3, ql = lane & 7;
  float s = 0.f;
  float acc[8] = {0.f,0.f,0.f,0.f,0.f,0.f,0.f,0.f};
  for (int e = p0 + g; e < p1; e += 8){
    int si = csr_src[e];
    float w = __expf(lrelu(el[si] + ern));
    uint4 v = *(const uint4*)(feat + (size_t)si*64 + ql*8);
    s += w;
    acc[0] += w*bflo(v.x); acc[1] += w*bfhi(v.x);
    acc[2] += w*bflo(v.y); acc[3] += w*bfhi(v.y);
    acc[4] += w*bflo(v.z); acc[5] += w*bfhi(v.z);
    acc[6] += w*bflo(v.w); acc[7] += w*bfhi(v.w);
  }
  #pragma unroll
  for (int m=8;m<64;m<<=1){
    s += __shfl_xor(s,m);
    #pragma unroll
    for (int i=0;i<8;++i) acc[i] += __shfl_xor(acc[i],m);
  }
  float inv = s > 0.f ? 1.f/s : 0.f;
  if (g == 0){
    float* op = out + (size_t)n*64 + ql*8;
    *(float4*)op     = make_float4(acc[0]*inv, acc[1]*inv, acc[2]*inv, acc[3]*inv);
    *(float4*)(op+4) = make_float4(acc[4]*inv, acc[5]*inv, acc[6]*inv, acc[7]*inv);
  }
}

extern "C" void kernel_launch(void* const* d_in, const int* in_sizes, int n_in,
                              void* d_out, int out_size, void* d_ws, size_t ws_size,
                              hipStream_t stream){
  const float* x   = (const float*)d_in[0];
  const float* W1  = (const float*)d_in[1];
  const float* al1 = (const float*)d_in[2];
  const float* ar1 = (const float*)d_in[3];
  const float* W2  = (const float*)d_in[4];
  const float* al2 = (const float*)d_in[5];
  const float* ar2 = (const float*)d_in[6];
  const int* src   = (const int*)d_in[7];
  const int* dst   = (const int*)d_in[8];
  float* out = (float*)d_out;

  char* ws = (char*)d_ws;
  size_t off = 0;
  auto alloc = [&](size_t bytes)->char*{
    char* p = ws + off; off += (bytes + 255) & ~(size_t)255; return p;
  };
  unsigned char*  feat1 = (unsigned char*)alloc((size_t)N_NODES*512);     // 51.2 MB fp8
  unsigned short* h1    = (unsigned short*)alloc((size_t)N_NODES*512*2);  // 102.4 MB
  unsigned short* feat2b = (unsigned short*)feat1;  // alias: feat1 dead after k_agg1
  unsigned short* W1t = (unsigned short*)alloc(512*128*2);
  unsigned short* W2t = (unsigned short*)alloc(64*512*2);
  float* el1 = (float*)alloc((size_t)N_NODES*4*4);
  float* er1 = (float*)alloc((size_t)N_NODES*4*4);
  float* el2 = el1;                           // alias: el1 dead after k_agg1
  float* er2 = er1;
  int* deg     = (int*)alloc((size_t)N_NODES*4);
  int* indptr  = (int*)alloc((size_t)(N_NODES+1)*4);
  int* cursor  = (int*)alloc((size_t)N_NODES*4);
  int* bsum    = (int*)alloc(512);
  int* boff    = (int*)alloc(512);
  int* csr_src = (int*)alloc((size_t)N_EDGES*4);                          // 12.8 MB
  // total ~171 MB (< proven 222 MB footprint)

  dim3 b256(256);
  k_zero<<<dim3((N_NODES+255)/256), b256, 0, stream>>>(deg, N_NODES);
  k_cvtW1<<<dim3(256), b256, 0, stream>>>(W1, W1t);
  k_cvtW2<<<dim3(128), b256, 0, stream>>>(W2, W2t);
  // layer 1 projection (MFMA) + fused scores; feat1 -> fp8
  k_mm1<<<dim3(782, 4), b256, 0, stream>>>(x, W1t, feat1, N_NODES, al1, ar1, el1, er1);
  // dst-CSR
  k_count<<<dim3((N_EDGES+255)/256), b256, 0, stream>>>(dst, deg);
  k_scan1<<<dim3(98), dim3(1024), 0, stream>>>(deg, indptr, bsum);
  k_scan2<<<dim3(1), dim3(128), 0, stream>>>(bsum, boff, 98);
  k_scan3<<<dim3((N_NODES+256)/256), b256, 0, stream>>>(indptr, boff, cursor);
  k_scatter<<<dim3((N_EDGES+255)/256), b256, 0, stream>>>(src, dst, cursor, csr_src);
  // layer-1 aggregate + ELU (single-pass, fp8 gather)
  k_agg1<<<dim3(25000), b256, 0, stream>>>(feat1, el1, er1, indptr, csr_src, h1);
  // layer 2 (MFMA) + fused scores
  k_mm2<<<dim3(782), b256, 0, stream>>>(h1, W2t, feat2b, N_NODES, al2, ar2, el2, er2);
  k_agg2<<<dim3(25000), b256, 0, stream>>>(feat2b, el2, er2, indptr, csr_src, out);
}